// Round 13
// baseline (598.807 us; speedup 1.0000x reference)
//
#include <hip/hip_runtime.h>

typedef _Float16 f16;
typedef _Float16 f16x4 __attribute__((ext_vector_type(4)));
typedef _Float16 f16x8 __attribute__((ext_vector_type(8)));
typedef float    f32x4 __attribute__((ext_vector_type(4)));

#define MFMA(a,b,c) __builtin_amdgcn_mfma_f32_16x16x32_f16(a,b,c,0,0,0)
#define SBAR() __builtin_amdgcn_sched_barrier(0)
#define BARRIER() do { SBAR(); __builtin_amdgcn_s_barrier(); SBAR(); } while (0)
#define VMCNT(n) do { SBAR(); asm volatile("s_waitcnt vmcnt(" #n ")" ::: "memory"); SBAR(); } while (0)

__device__ __forceinline__ void gload_lds16(const f16* g, f16* l) {
  __builtin_amdgcn_global_load_lds(
      (const __attribute__((address_space(1))) unsigned int*)g,
      (__attribute__((address_space(3))) unsigned int*)l, 16, 0, 0);
}

// ---------------------------------------------------------------------------
// f32 -> f16 elementwise convert (weights only)
// ---------------------------------------------------------------------------
__global__ __launch_bounds__(256)
void tof16_kernel(const float* __restrict__ x, f16* __restrict__ y, int n4) {
  int i = blockIdx.x * 256 + threadIdx.x;
  if (i >= n4) return;
  f32x4 v = ((const f32x4*)x)[i];
  f16x4 h;
#pragma unroll
  for (int j = 0; j < 4; j++) h[j] = (f16)v[j];
  ((f16x4*)y)[i] = h;
}

// ---------------------------------------------------------------------------
// Fused convert + transpose: in f32 [z][2048][1024]
//   -> rm f16 [z][2048][1024] (row-major)  and  tr f16 [z][1024][2048]
// ---------------------------------------------------------------------------
__global__ __launch_bounds__(256)
void prep_f16_kernel(const float* __restrict__ in, f16* __restrict__ rm,
                     f16* __restrict__ tr) {
  __shared__ f16 t[64][68];
  const int tid = threadIdx.x;
  const size_t z = blockIdx.z;
  const int n0 = blockIdx.x * 64, h0 = blockIdx.y * 64;
  const int rr = tid >> 4, cc = (tid & 15) * 4;
#pragma unroll
  for (int p = 0; p < 4; p++) {
    int n = rr + p * 16;
    f32x4 v = *(const f32x4*)(in + ((size_t)z * 2048 + n0 + n) * 1024 + h0 + cc);
    f16x4 h;
#pragma unroll
    for (int j = 0; j < 4; j++) h[j] = (f16)v[j];
    *(f16x4*)&t[n][cc] = h;
    *(f16x4*)(rm + ((size_t)z * 2048 + n0 + n) * 1024 + h0 + cc) = h;
  }
  __syncthreads();
#pragma unroll
  for (int p = 0; p < 4; p++) {
    int h = rr + p * 16;
    f16x4 o;
#pragma unroll
    for (int j = 0; j < 4; j++) o[j] = t[cc + j][h];
    *(f16x4*)(tr + ((size_t)z * 1024 + h0 + h) * 2048 + n0 + cc) = o;
  }
}

// ---------------------------------------------------------------------------
// 256x128-tile GEMM, register-pipelined (forced LDS/MFMA overlap), RACE-FIXED:
//   C = A(f16,[M][K],lda) * B(f16,[N][K],ldb)^T
// 8 waves (4M x 2N), per-wave 64x64: acc[4][4] + two alternating fragment
// sets S0/S1. Window t (ONE barrier):
//   STAGE(t+1 -> buf c^1) | RD kk1(t)->S1 | 16 MFMA kk0(t) from PRELOADED S0
//   (zero lgkm dep -- issues immediately, overlapping S1's ds_reads) |
//   16 MFMA kk1(t) | vmcnt(0) | s_barrier | RD kk0(t+1)->S0.
// The barrier between vmcnt(0) and RD_S0 is the r12 race fix: vmcnt only
// guarantees the wave's OWN global_load_lds landed; the barrier (each wave
// having drained vmcnt before it) makes all waves' stages visible before
// any cross-wave read. WAR on buf c^1: its last readers (RD_S1@t-1,
// RD_S0@t-2) complete before BARRIER(t-1), STAGE@t is after it.
// LDS: 2 bufs x (A 256x64 + B 128x64) = 96 KB. XOR-chunk swizzle
// (chunk ^= row&7) via pre-swizzled global source; conflict-free b128 reads.
// Block mapping (batch-per-XCD): z = id % ZB, k = id / ZB; bx = k % gx,
// by = k / gx.
// ---------------------------------------------------------------------------
template <int OUTF32>
__global__ __launch_bounds__(512, 2)
void gemm_rp(const f16* __restrict__ Ag, size_t zA,
             const f16* __restrict__ Bg, size_t zB,
             void* __restrict__ Cg, size_t zC,
             int lda, int ldb, int ldc, int K, int ZB, int gx) {
  __shared__ f16 sm[2][24576];  // [buf][A:256*64 | B:128*64], 96 KB
  const int tid = threadIdx.x;
  const int id = blockIdx.x;
  const size_t z = id % ZB;
  const int k = id / ZB;
  const int bx = k % gx, by = k / gx;
  const f16* A = Ag + z * zA + (size_t)bx * 256 * lda;
  const f16* B = Bg + z * zB + (size_t)by * 128 * ldb;

  const int lane = tid & 63, w = tid >> 6;
  const int wm = w >> 1, wn = w & 1;
  const int lr = lane & 15, kg = lane >> 4;
  // swizzled chunk offsets (halfs) for kk0 / kk1 fragment reads
  const int sx0 = ((kg ^ (lr & 7)) << 3);
  const int sx1 = (((4 + kg) ^ (lr & 7)) << 3);
  const int aoff = (wm * 64 + lr) * 64;            // + fm*1024 + sx
  const int boff = 16384 + (wn * 64 + lr) * 64;    // + fn*1024 + sx
  // staging: 512 threads, 8 lanes/row (64 halfs), 64 rows/round
  const int srow = tid >> 3;                       // 0..63
  const int gcolx = (((tid & 7) ^ (srow & 7)) << 3);  // pre-swizzled src col
  const int wls = w * 512;                         // wave-uniform dest (halfs)

  f32x4 acc[4][4] = {};
  f16x8 a0[4], b0[4], a1[4], b1[4];  // S0 (kk0, preloaded) / S1 (kk1)

  // stage tile into buf cc: A 4 rounds (256 rows), B 2 rounds (128 rows)
#define STAGE(cc, ktc) do {                                                    \
    _Pragma("unroll")                                                          \
    for (int p = 0; p < 4; p++)                                                \
      gload_lds16(A + (size_t)(p * 64 + srow) * lda + (ktc) + gcolx,           \
                  &sm[cc][p * 4096 + wls]);                                    \
    _Pragma("unroll")                                                          \
    for (int p = 0; p < 2; p++)                                                \
      gload_lds16(B + (size_t)(p * 64 + srow) * ldb + (ktc) + gcolx,           \
                  &sm[cc][16384 + p * 4096 + wls]);                            \
  } while (0)

#define RD_S0(cc) do { _Pragma("unroll")                                       \
    for (int i = 0; i < 4; i++) {                                              \
      a0[i] = *(const f16x8*)&sm[cc][aoff + i * 1024 + sx0];                   \
      b0[i] = *(const f16x8*)&sm[cc][boff + i * 1024 + sx0];                   \
    } } while (0)

#define RD_S1(cc) do { _Pragma("unroll")                                       \
    for (int i = 0; i < 4; i++) {                                              \
      a1[i] = *(const f16x8*)&sm[cc][aoff + i * 1024 + sx1];                   \
      b1[i] = *(const f16x8*)&sm[cc][boff + i * 1024 + sx1];                   \
    } } while (0)

#define MFMA16(aa, bb) do {                                                    \
    __builtin_amdgcn_s_setprio(1);                                             \
    _Pragma("unroll")                                                          \
    for (int fm = 0; fm < 4; fm++) { _Pragma("unroll")                         \
      for (int fn = 0; fn < 4; fn++)                                           \
        acc[fm][fn] = MFMA(aa[fm], bb[fn], acc[fm][fn]);                       \
    }                                                                          \
    __builtin_amdgcn_s_setprio(0);                                             \
  } while (0)

  const int nt = K >> 6;
  // prologue: stage tile 0 into buf 0; make cross-wave visible; preload kk0
  STAGE(0, 0);
  VMCNT(0);
  BARRIER();
  RD_S0(0);

  for (int t = 0; t < nt - 1; ++t) {
    const int c = t & 1;
    STAGE(c ^ 1, (t + 1) << 6);   // tile t+1 -> other buffer
    RD_S1(c);                     // kk1(t) reads stream under kk0 MFMAs
    MFMA16(a0, b0);               // kk0(t): operands preloaded, no lgkm dep
    MFMA16(a1, b1);               // kk1(t): waits only on RD_S1
    VMCNT(0);                     // own stage of tile t+1 retired
    BARRIER();                    // ALL waves' stages visible; buf-c reads done
    RD_S0(c ^ 1);                 // preload kk0(t+1)  [race-fixed: post-barrier]
  }
  {  // last tile
    const int c = (nt - 1) & 1;
    RD_S1(c);
    MFMA16(a0, b0);
    MFMA16(a1, b1);
  }

#pragma unroll
  for (int fm = 0; fm < 4; fm++)
#pragma unroll
    for (int fn = 0; fn < 4; fn++)
#pragma unroll
      for (int q = 0; q < 4; q++) {
        size_t grow = (size_t)bx * 256 + wm * 64 + fm * 16 + kg * 4 + q;
        int gcol = by * 128 + wn * 64 + fn * 16 + lr;
        if (OUTF32)
          ((float*)Cg)[z * zC + grow * ldc + gcol] = acc[fm][fn][q];
        else
          ((f16*)Cg)[z * zC + grow * ldc + gcol] = (f16)acc[fm][fn][q];
      }
#undef STAGE
#undef RD_S0
#undef RD_S1
#undef MFMA16
}

// ---------------------------------------------------------------------------
// Row softmax: SC row (2048 f32) -> Pb row (2048 f16)
// ---------------------------------------------------------------------------
__global__ __launch_bounds__(256)
void softmax_rows(const float* __restrict__ SC, f16* __restrict__ Pb) {
  const float* r = SC + (size_t)blockIdx.x * 2048;
  f16* po = Pb + (size_t)blockIdx.x * 2048;
  const int tid = threadIdx.x;
  f32x4 a = *(const f32x4*)(r + tid * 8);
  f32x4 b = *(const f32x4*)(r + tid * 8 + 4);
  float x[8] = {a[0], a[1], a[2], a[3], b[0], b[1], b[2], b[3]};
#pragma unroll
  for (int i = 0; i < 8; i++) x[i] = fminf(fmaxf(x[i], -1e30f), 1e30f);
  float m = x[0];
#pragma unroll
  for (int i = 1; i < 8; i++) m = fmaxf(m, x[i]);
#pragma unroll
  for (int off = 32; off; off >>= 1) m = fmaxf(m, __shfl_xor(m, off));
  __shared__ float rmax[4], rsum[4];
  const int w = tid >> 6, lane = tid & 63;
  if (!lane) rmax[w] = m;
  __syncthreads();
  m = fmaxf(fmaxf(rmax[0], rmax[1]), fmaxf(rmax[2], rmax[3]));
  float e[8], s = 0.f;
#pragma unroll
  for (int i = 0; i < 8; i++) {
    e[i] = __expf(x[i] - m);
    s += e[i];
  }
#pragma unroll
  for (int off = 32; off; off >>= 1) s += __shfl_xor(s, off);
  if (!lane) rsum[w] = s;
  __syncthreads();
  s = rsum[0] + rsum[1] + rsum[2] + rsum[3];
  float inv = 1.0f / s;
  f16x8 p;
#pragma unroll
  for (int i = 0; i < 8; i++) p[i] = (f16)(e[i] * inv);
  *(f16x8*)(po + tid * 8) = p;
}

// ---------------------------------------------------------------------------
extern "C" void kernel_launch(void* const* d_in, const int* in_sizes, int n_in,
                              void* d_out, int out_size, void* d_ws, size_t ws_size,
                              hipStream_t stream) {
  const float* S1 = (const float*)d_in[0];
  const float* S2 = (const float*)d_in[1];
  const float* W1 = (const float*)d_in[2];
  const float* W2 = (const float*)d_in[3];
  float* out = (float*)d_out;
  const int B = 8, N = 2048, H = 1024;
  const size_t NH = (size_t)N * H;  // 2M elems
  const size_t NN = (size_t)N * N;  // 4M elems
  const size_t WN = (size_t)H * H;  // 1M elems

  char* ws = (char*)d_ws;
  f16* W1h = (f16*)ws;
  f16* W2h = W1h + WN;
  size_t fixed = 2 * WN * sizeof(f16);  // 4 MB
  size_t perb = 5 * NH * sizeof(f16) + NN * sizeof(float) + NN * sizeof(f16);

  int bc = 1;
  const int cands[4] = {8, 4, 2, 1};
  for (int ci = 0; ci < 4; ci++) {
    if (fixed + (size_t)cands[ci] * perb <= ws_size) { bc = cands[ci]; break; }
  }
  f16* Ah = (f16*)(ws + fixed);       // S1 chunk f16
  f16* Bh = Ah + (size_t)bc * NH;     // S2 chunk f16
  f16* At = Bh + (size_t)bc * NH;     // S1 chunk transposed f16 [z][1024][2048]
  f16* Bt = At + (size_t)bc * NH;     // S2 chunk transposed
  f16* Kh = Bt + (size_t)bc * NH;     // proj output
  float* SC = (float*)(Kh + (size_t)bc * NH);
  f16* Pb = (f16*)(SC + (size_t)bc * NN);

  {
    int n4 = (int)(WN / 4);
    tof16_kernel<<<dim3((n4 + 255) / 256), 256, 0, stream>>>(W1, W1h, n4);
    tof16_kernel<<<dim3((n4 + 255) / 256), 256, 0, stream>>>(W2, W2h, n4);
  }

  for (int c0 = 0; c0 < B; c0 += bc) {
    prep_f16_kernel<<<dim3(N / 64, H / 64, bc), 256, 0, stream>>>(
        S1 + (size_t)c0 * NH, Ah, At);
    prep_f16_kernel<<<dim3(N / 64, H / 64, bc), 256, 0, stream>>>(
        S2 + (size_t)c0 * NH, Bh, Bt);

    for (int path = 0; path < 2; path++) {
      const f16* Qh = path ? Bh : Ah;  // query side (f16)
      const f16* Xh = path ? Ah : Bh;  // proj input (f16)
      const f16* Vt = path ? At : Bt;  // V transposed [z][1024][2048]
      const f16* Wh = path ? W2h : W1h;
      float* Op = out + (size_t)path * B * NH + (size_t)c0 * NH;

      // Kh = Xh @ W^T : M = bc*2048 (bx=bc*8), N = 1024 (by=8), K = 1024
      gemm_rp<0><<<dim3(bc * 64), 512, 0, stream>>>(
          Xh, 0, Wh, 0, Kh, 0, H, H, H, H, 1, bc * 8);
      // SC = Qh @ Kh^T per batch: 2048x2048 (bx=8, by=16), K = 1024
      gemm_rp<1><<<dim3(bc * 128), 512, 0, stream>>>(
          Qh, NH, Kh, NH, SC, NN, H, H, N, H, bc, 8);
      // softmax rows -> Pb f16
      softmax_rows<<<dim3(bc * N), 256, 0, stream>>>(SC, Pb);
      // O = Pb @ Vt^T : per batch 2048x1024 (bx=8, by=8), K = 2048
      gemm_rp<1><<<dim3(bc * 64), 512, 0, stream>>>(
          Pb, NN, Vt, NH, Op, NH, N, N, H, N, bc, 8);
    }
  }
}

// Round 14
// 561.570 us; speedup vs baseline: 1.0663x; 1.0663x over previous
//
#include <hip/hip_runtime.h>

typedef _Float16 f16;
typedef _Float16 f16x4 __attribute__((ext_vector_type(4)));
typedef _Float16 f16x8 __attribute__((ext_vector_type(8)));
typedef float    f32x4 __attribute__((ext_vector_type(4)));

#define MFMA(a,b,c) __builtin_amdgcn_mfma_f32_16x16x32_f16(a,b,c,0,0,0)
#define SBAR() __builtin_amdgcn_sched_barrier(0)
#define BARRIER() do { SBAR(); __builtin_amdgcn_s_barrier(); SBAR(); } while (0)
#define VMCNT(n) do { SBAR(); asm volatile("s_waitcnt vmcnt(" #n ")" ::: "memory"); SBAR(); } while (0)

__device__ __forceinline__ void gload_lds16(const f16* g, f16* l) {
  __builtin_amdgcn_global_load_lds(
      (const __attribute__((address_space(1))) unsigned int*)g,
      (__attribute__((address_space(3))) unsigned int*)l, 16, 0, 0);
}

// ---------------------------------------------------------------------------
// f32 -> f16 elementwise convert (weights only)
// ---------------------------------------------------------------------------
__global__ __launch_bounds__(256)
void tof16_kernel(const float* __restrict__ x, f16* __restrict__ y, int n4) {
  int i = blockIdx.x * 256 + threadIdx.x;
  if (i >= n4) return;
  f32x4 v = ((const f32x4*)x)[i];
  f16x4 h;
#pragma unroll
  for (int j = 0; j < 4; j++) h[j] = (f16)v[j];
  ((f16x4*)y)[i] = h;
}

// ---------------------------------------------------------------------------
// Fused convert + transpose: in f32 [z][2048][1024]
//   -> rm f16 [z][2048][1024] (row-major)  and  tr f16 [z][1024][2048]
// ---------------------------------------------------------------------------
__global__ __launch_bounds__(256)
void prep_f16_kernel(const float* __restrict__ in, f16* __restrict__ rm,
                     f16* __restrict__ tr) {
  __shared__ f16 t[64][68];
  const int tid = threadIdx.x;
  const size_t z = blockIdx.z;
  const int n0 = blockIdx.x * 64, h0 = blockIdx.y * 64;
  const int rr = tid >> 4, cc = (tid & 15) * 4;
#pragma unroll
  for (int p = 0; p < 4; p++) {
    int n = rr + p * 16;
    f32x4 v = *(const f32x4*)(in + ((size_t)z * 2048 + n0 + n) * 1024 + h0 + cc);
    f16x4 h;
#pragma unroll
    for (int j = 0; j < 4; j++) h[j] = (f16)v[j];
    *(f16x4*)&t[n][cc] = h;
    *(f16x4*)(rm + ((size_t)z * 2048 + n0 + n) * 1024 + h0 + cc) = h;
  }
  __syncthreads();
#pragma unroll
  for (int p = 0; p < 4; p++) {
    int h = rr + p * 16;
    f16x4 o;
#pragma unroll
    for (int j = 0; j < 4; j++) o[j] = t[cc + j][h];
    *(f16x4*)(tr + ((size_t)z * 1024 + h0 + h) * 2048 + n0 + cc) = o;
  }
}

// ---------------------------------------------------------------------------
// 256x128-tile GEMM, register-pipelined + DEEP staging (lead 2, vmcnt(6)):
//   C = A(f16,[M][K],lda) * B(f16,[N][K],ldb)^T
// 8 waves (4M x 2N), per-wave 64x64. THREE 24 KB LDS buffers (72 KB), tile
// t+2 staged during window t; the counted vmcnt(6) at window end waits only
// for tile t+1's units -- issued one full window (~1600+ cyc) earlier, so
// HBM-miss latency (~900 cyc) is covered (r13's vmcnt(0) waited for loads
// issued ~200 cyc earlier -- the measured stall). Window t (ONE barrier):
//   STAGE(t+2) | RD kk1(t)->S1 | 16 MFMA kk0(t) from PRELOADED S0 (zero
//   lgkm dep, issues under S1's ds_reads) | 16 MFMA kk1(t) | vmcnt(6) |
//   s_barrier | RD kk0(t+1)->S0.
// Hazards: RAW -- every wave drains vmcnt(6) (tile t+1 complete) before the
// barrier; all cross-wave reads of t+1 are post-barrier. WAR -- STAGE(t+2)
// overwrites tile t-1's buffer, whose last readers retired before
// BARRIER(t-1) (MFMA lgkm dependency), one full barrier earlier.
// XOR-chunk swizzle via pre-swizzled global source; conflict-free b128 reads.
// Block mapping (batch-per-XCD): z = id % ZB, k = id / ZB; bx=k%gx, by=k/gx.
// ---------------------------------------------------------------------------
template <int OUTF32>
__global__ __launch_bounds__(512, 2)
void gemm_rp(const f16* __restrict__ Ag, size_t zA,
             const f16* __restrict__ Bg, size_t zB,
             void* __restrict__ Cg, size_t zC,
             int lda, int ldb, int ldc, int K, int ZB, int gx) {
  __shared__ f16 sm[3][24576];  // [buf][A:256*64 | B:128*64], 72 KB
  const int tid = threadIdx.x;
  const int id = blockIdx.x;
  const size_t z = id % ZB;
  const int k = id / ZB;
  const int bx = k % gx, by = k / gx;
  const f16* A = Ag + z * zA + (size_t)bx * 256 * lda;
  const f16* B = Bg + z * zB + (size_t)by * 128 * ldb;

  const int lane = tid & 63, w = tid >> 6;
  const int wm = w >> 1, wn = w & 1;
  const int lr = lane & 15, kg = lane >> 4;
  // swizzled chunk offsets (halfs) for kk0 / kk1 fragment reads
  const int sx0 = ((kg ^ (lr & 7)) << 3);
  const int sx1 = (((4 + kg) ^ (lr & 7)) << 3);
  const int aoff = (wm * 64 + lr) * 64;            // + fm*1024 + sx
  const int boff = 16384 + (wn * 64 + lr) * 64;    // + fn*1024 + sx
  // staging: 512 threads, 8 lanes/row (64 halfs), 64 rows/round
  const int srow = tid >> 3;                       // 0..63
  const int gcolx = (((tid & 7) ^ (srow & 7)) << 3);  // pre-swizzled src col
  const int wls = w * 512;                         // wave-uniform dest (halfs)

  f32x4 acc[4][4] = {};
  f16x8 a0[4], b0[4], a1[4], b1[4];  // S0 (kk0, preloaded) / S1 (kk1)

  // stage tile into buf cc: A 4 rounds (256 rows), B 2 rounds (128 rows)
#define STAGE(cc, ktc) do {                                                    \
    _Pragma("unroll")                                                          \
    for (int p = 0; p < 4; p++)                                                \
      gload_lds16(A + (size_t)(p * 64 + srow) * lda + (ktc) + gcolx,           \
                  &sm[cc][p * 4096 + wls]);                                    \
    _Pragma("unroll")                                                          \
    for (int p = 0; p < 2; p++)                                                \
      gload_lds16(B + (size_t)(p * 64 + srow) * ldb + (ktc) + gcolx,           \
                  &sm[cc][16384 + p * 4096 + wls]);                            \
  } while (0)

#define RD_S0(cc) do { _Pragma("unroll")                                       \
    for (int i = 0; i < 4; i++) {                                              \
      a0[i] = *(const f16x8*)&sm[cc][aoff + i * 1024 + sx0];                   \
      b0[i] = *(const f16x8*)&sm[cc][boff + i * 1024 + sx0];                   \
    } } while (0)

#define RD_S1(cc) do { _Pragma("unroll")                                       \
    for (int i = 0; i < 4; i++) {                                              \
      a1[i] = *(const f16x8*)&sm[cc][aoff + i * 1024 + sx1];                   \
      b1[i] = *(const f16x8*)&sm[cc][boff + i * 1024 + sx1];                   \
    } } while (0)

#define MFMA16(aa, bb) do {                                                    \
    __builtin_amdgcn_s_setprio(1);                                             \
    _Pragma("unroll")                                                          \
    for (int fm = 0; fm < 4; fm++) { _Pragma("unroll")                         \
      for (int fn = 0; fn < 4; fn++)                                           \
        acc[fm][fn] = MFMA(aa[fm], bb[fn], acc[fm][fn]);                       \
    }                                                                          \
    __builtin_amdgcn_s_setprio(0);                                             \
  } while (0)

  const int nt = K >> 6;   // >= 3 for all our shapes (16 or 32)
  // prologue: stage tiles 0,1; wait tile 0 (newest 6 = tile 1 stay in flight)
  STAGE(0, 0);
  STAGE(1, 64);
  VMCNT(6);
  BARRIER();
  RD_S0(0);

  for (int t = 0; t < nt - 2; ++t) {
    const int c = t % 3;
    const int cn = (t + 1) % 3;
    STAGE((t + 2) % 3, (t + 2) << 6);  // tile t+2 (overwrites t-1's buffer)
    RD_S1(c);                          // kk1(t) streams under kk0 MFMAs
    MFMA16(a0, b0);                    // kk0(t): preloaded, zero lgkm dep
    MFMA16(a1, b1);                    // kk1(t)
    VMCNT(6);                          // tile t+1 complete; t+2's 6 in flight
    BARRIER();                         // all waves' t+1 stages visible
    RD_S0(cn);                         // preload kk0(t+1)
  }
  {  // window nt-2: no staging; drain all for the last tile
    const int c = (nt - 2) % 3;
    RD_S1(c);
    MFMA16(a0, b0);
    MFMA16(a1, b1);
    VMCNT(0);
    BARRIER();
    RD_S0((nt - 1) % 3);
  }
  {  // last tile
    RD_S1((nt - 1) % 3);
    MFMA16(a0, b0);
    MFMA16(a1, b1);
  }

#pragma unroll
  for (int fm = 0; fm < 4; fm++)
#pragma unroll
    for (int fn = 0; fn < 4; fn++)
#pragma unroll
      for (int q = 0; q < 4; q++) {
        size_t grow = (size_t)bx * 256 + wm * 64 + fm * 16 + kg * 4 + q;
        int gcol = by * 128 + wn * 64 + fn * 16 + lr;
        if (OUTF32)
          ((float*)Cg)[z * zC + grow * ldc + gcol] = acc[fm][fn][q];
        else
          ((f16*)Cg)[z * zC + grow * ldc + gcol] = (f16)acc[fm][fn][q];
      }
#undef STAGE
#undef RD_S0
#undef RD_S1
#undef MFMA16
}

// ---------------------------------------------------------------------------
// Row softmax: SC row (2048 f32) -> Pb row (2048 f16)
// ---------------------------------------------------------------------------
__global__ __launch_bounds__(256)
void softmax_rows(const float* __restrict__ SC, f16* __restrict__ Pb) {
  const float* r = SC + (size_t)blockIdx.x * 2048;
  f16* po = Pb + (size_t)blockIdx.x * 2048;
  const int tid = threadIdx.x;
  f32x4 a = *(const f32x4*)(r + tid * 8);
  f32x4 b = *(const f32x4*)(r + tid * 8 + 4);
  float x[8] = {a[0], a[1], a[2], a[3], b[0], b[1], b[2], b[3]};
#pragma unroll
  for (int i = 0; i < 8; i++) x[i] = fminf(fmaxf(x[i], -1e30f), 1e30f);
  float m = x[0];
#pragma unroll
  for (int i = 1; i < 8; i++) m = fmaxf(m, x[i]);
#pragma unroll
  for (int off = 32; off; off >>= 1) m = fmaxf(m, __shfl_xor(m, off));
  __shared__ float rmax[4], rsum[4];
  const int w = tid >> 6, lane = tid & 63;
  if (!lane) rmax[w] = m;
  __syncthreads();
  m = fmaxf(fmaxf(rmax[0], rmax[1]), fmaxf(rmax[2], rmax[3]));
  float e[8], s = 0.f;
#pragma unroll
  for (int i = 0; i < 8; i++) {
    e[i] = __expf(x[i] - m);
    s += e[i];
  }
#pragma unroll
  for (int off = 32; off; off >>= 1) s += __shfl_xor(s, off);
  if (!lane) rsum[w] = s;
  __syncthreads();
  s = rsum[0] + rsum[1] + rsum[2] + rsum[3];
  float inv = 1.0f / s;
  f16x8 p;
#pragma unroll
  for (int i = 0; i < 8; i++) p[i] = (f16)(e[i] * inv);
  *(f16x8*)(po + tid * 8) = p;
}

// ---------------------------------------------------------------------------
extern "C" void kernel_launch(void* const* d_in, const int* in_sizes, int n_in,
                              void* d_out, int out_size, void* d_ws, size_t ws_size,
                              hipStream_t stream) {
  const float* S1 = (const float*)d_in[0];
  const float* S2 = (const float*)d_in[1];
  const float* W1 = (const float*)d_in[2];
  const float* W2 = (const float*)d_in[3];
  float* out = (float*)d_out;
  const int B = 8, N = 2048, H = 1024;
  const size_t NH = (size_t)N * H;  // 2M elems
  const size_t NN = (size_t)N * N;  // 4M elems
  const size_t WN = (size_t)H * H;  // 1M elems

  char* ws = (char*)d_ws;
  f16* W1h = (f16*)ws;
  f16* W2h = W1h + WN;
  size_t fixed = 2 * WN * sizeof(f16);  // 4 MB
  size_t perb = 5 * NH * sizeof(f16) + NN * sizeof(float) + NN * sizeof(f16);

  int bc = 1;
  const int cands[4] = {8, 4, 2, 1};
  for (int ci = 0; ci < 4; ci++) {
    if (fixed + (size_t)cands[ci] * perb <= ws_size) { bc = cands[ci]; break; }
  }
  f16* Ah = (f16*)(ws + fixed);       // S1 chunk f16
  f16* Bh = Ah + (size_t)bc * NH;     // S2 chunk f16
  f16* At = Bh + (size_t)bc * NH;     // S1 chunk transposed f16 [z][1024][2048]
  f16* Bt = At + (size_t)bc * NH;     // S2 chunk transposed
  f16* Kh = Bt + (size_t)bc * NH;     // proj output
  float* SC = (float*)(Kh + (size_t)bc * NH);
  f16* Pb = (f16*)(SC + (size_t)bc * NN);

  {
    int n4 = (int)(WN / 4);
    tof16_kernel<<<dim3((n4 + 255) / 256), 256, 0, stream>>>(W1, W1h, n4);
    tof16_kernel<<<dim3((n4 + 255) / 256), 256, 0, stream>>>(W2, W2h, n4);
  }

  for (int c0 = 0; c0 < B; c0 += bc) {
    prep_f16_kernel<<<dim3(N / 64, H / 64, bc), 256, 0, stream>>>(
        S1 + (size_t)c0 * NH, Ah, At);
    prep_f16_kernel<<<dim3(N / 64, H / 64, bc), 256, 0, stream>>>(
        S2 + (size_t)c0 * NH, Bh, Bt);

    for (int path = 0; path < 2; path++) {
      const f16* Qh = path ? Bh : Ah;  // query side (f16)
      const f16* Xh = path ? Ah : Bh;  // proj input (f16)
      const f16* Vt = path ? At : Bt;  // V transposed [z][1024][2048]
      const f16* Wh = path ? W2h : W1h;
      float* Op = out + (size_t)path * B * NH + (size_t)c0 * NH;

      // Kh = Xh @ W^T : M = bc*2048 (bx=bc*8), N = 1024 (by=8), K = 1024
      gemm_rp<0><<<dim3(bc * 64), 512, 0, stream>>>(
          Xh, 0, Wh, 0, Kh, 0, H, H, H, H, 1, bc * 8);
      // SC = Qh @ Kh^T per batch: 2048x2048 (bx=8, by=16), K = 1024
      gemm_rp<1><<<dim3(bc * 128), 512, 0, stream>>>(
          Qh, NH, Kh, NH, SC, NN, H, H, N, H, bc, 8);
      // softmax rows -> Pb f16
      softmax_rows<<<dim3(bc * N), 256, 0, stream>>>(SC, Pb);
      // O = Pb @ Vt^T : per batch 2048x1024 (bx=8, by=8), K = 2048
      gemm_rp<1><<<dim3(bc * 64), 512, 0, stream>>>(
          Pb, NN, Vt, NH, Op, NH, N, N, H, N, bc, 8);
    }
  }
}

// Round 15
// 493.571 us; speedup vs baseline: 1.2132x; 1.1378x over previous
//
#include <hip/hip_runtime.h>

typedef _Float16 f16;
typedef _Float16 f16x4 __attribute__((ext_vector_type(4)));
typedef _Float16 f16x8 __attribute__((ext_vector_type(8)));
typedef float    f32x4 __attribute__((ext_vector_type(4)));

#define MFMA(a,b,c) __builtin_amdgcn_mfma_f32_16x16x32_f16(a,b,c,0,0,0)
#define SBAR() __builtin_amdgcn_sched_barrier(0)
#define BARRIER() do { SBAR(); __builtin_amdgcn_s_barrier(); SBAR(); } while (0)
#define VMCNT(n) do { SBAR(); asm volatile("s_waitcnt vmcnt(" #n ")" ::: "memory"); SBAR(); } while (0)
#define LGKM0() do { asm volatile("s_waitcnt lgkmcnt(0)" ::: "memory"); SBAR(); } while (0)

__device__ __forceinline__ void gload_lds16(const f16* g, f16* l) {
  __builtin_amdgcn_global_load_lds(
      (const __attribute__((address_space(1))) unsigned int*)g,
      (__attribute__((address_space(3))) unsigned int*)l, 16, 0, 0);
}

// ---------------------------------------------------------------------------
// f32 -> f16 convert for BOTH weight matrices in one dispatch (y decodes)
// ---------------------------------------------------------------------------
__global__ __launch_bounds__(256)
void tof16x2_kernel(const float* __restrict__ w1, const float* __restrict__ w2,
                    f16* __restrict__ y1, f16* __restrict__ y2, int n4) {
  int i = blockIdx.x * 256 + threadIdx.x;
  if (i >= n4) return;
  const float* x = blockIdx.y ? w2 : w1;
  f16* y = blockIdx.y ? y2 : y1;
  f32x4 v = ((const f32x4*)x)[i];
  f16x4 h;
#pragma unroll
  for (int j = 0; j < 4; j++) h[j] = (f16)v[j];
  ((f16x4*)y)[i] = h;
}

// ---------------------------------------------------------------------------
// Fused convert + transpose for BOTH S chunks in one dispatch (z decodes):
// in f32 [z][2048][1024] -> rm f16 [z][2048][1024] and tr f16 [z][1024][2048]
// ---------------------------------------------------------------------------
__global__ __launch_bounds__(256)
void prep2_f16_kernel(const float* __restrict__ s1, const float* __restrict__ s2,
                      f16* __restrict__ rm1, f16* __restrict__ tr1,
                      f16* __restrict__ rm2, f16* __restrict__ tr2, int bc) {
  __shared__ f16 t[64][68];
  const int tid = threadIdx.x;
  const int zz = blockIdx.z;
  const int sel = zz >= bc;
  const size_t z = sel ? (zz - bc) : zz;
  const float* in = sel ? s2 : s1;
  f16* rm = sel ? rm2 : rm1;
  f16* tr = sel ? tr2 : tr1;
  const int n0 = blockIdx.x * 64, h0 = blockIdx.y * 64;
  const int rr = tid >> 4, cc = (tid & 15) * 4;
#pragma unroll
  for (int p = 0; p < 4; p++) {
    int n = rr + p * 16;
    f32x4 v = *(const f32x4*)(in + ((size_t)z * 2048 + n0 + n) * 1024 + h0 + cc);
    f16x4 h;
#pragma unroll
    for (int j = 0; j < 4; j++) h[j] = (f16)v[j];
    *(f16x4*)&t[n][cc] = h;
    *(f16x4*)(rm + ((size_t)z * 2048 + n0 + n) * 1024 + h0 + cc) = h;
  }
  __syncthreads();
#pragma unroll
  for (int p = 0; p < 4; p++) {
    int h = rr + p * 16;
    f16x4 o;
#pragma unroll
    for (int j = 0; j < 4; j++) o[j] = t[cc + j][h];
    *(f16x4*)(tr + ((size_t)z * 1024 + h0 + h) * 2048 + n0 + cc) = o;
  }
}

// ---------------------------------------------------------------------------
// 256x256-tile 4-phase GEMM (r7, best measured: 838 TF):
//   C = A(f16,[M][K],lda) * B(f16,[N][K],ldb)^T
// Block mapping (batch-per-XCD): z = id % ZB (consecutive ids round-robin
// XCDs -> XCD owns batch z), k = id / ZB; bx = k % gx, by = k / gx.
// Schedule: pre-barrier ds_read + 1-unit stage, barrier, lgkmcnt(0),
// setprio+16 MFMA, checkpointed vmcnt(4) (one barrier ahead of the phase
// that reads the guarded unit), barrier.
// ---------------------------------------------------------------------------
template <int OUTF32>
__global__ __launch_bounds__(512, 2)
void gemm256(const f16* __restrict__ Ag, size_t zA,
             const f16* __restrict__ Bg, size_t zB,
             void* __restrict__ Cg, size_t zC,
             int lda, int ldb, int ldc, int K, int ZB, int gx) {
  __shared__ f16 sm[8][8192];  // [c*4 + mat*2 + kk][256*32], 128 KB
  const int tid = threadIdx.x;
  const int id = blockIdx.x;
  const size_t z = id % ZB;
  const int k = id / ZB;
  const int bx = k % gx, by = k / gx;
  const f16* A = Ag + z * zA + (size_t)bx * 256 * lda;
  const f16* B = Bg + z * zB + (size_t)by * 256 * ldb;

  const int lane = tid & 63, w = tid >> 6;
  const int wm = w >> 2, wn = w & 3;
  const int lr = lane & 15, kg = lane >> 4;
  const int sx = (kg ^ ((lr >> 1) & 3)) << 3;      // swizzled chunk for reads
  const int aoff = wm * 4096 + lr * 32 + sx;
  const int boff = wn * 2048 + lr * 32 + sx;
  const int colx = (((tid & 3) ^ ((tid >> 3) & 3)) << 3);  // pre-swizzled src col
  const int srow = tid >> 2;
  const int wls = w * 512;  // wave-uniform LDS base (halfs) per issue

  f32x4 acc[8][4] = {};
  f16x8 af[8], bf0, bf1;

#define STAGE(cc, mat, kkv, ktc) do {                                          \
    const f16* gs = ((mat) ? B : A) + (size_t)srow * ((mat) ? ldb : lda) +     \
                    (ktc) + (kkv) * 32 + colx;                                 \
    f16* ls = &sm[(cc) * 4 + (mat) * 2 + (kkv)][wls];                          \
    gload_lds16(gs, ls);                                                       \
    gload_lds16(gs + (size_t)128 * ((mat) ? ldb : lda), ls + 4096);            \
  } while (0)

#define LOAD_A(cc, kkv) do { _Pragma("unroll")                                 \
    for (int fm = 0; fm < 8; fm++)                                             \
      af[fm] = *(const f16x8*)&sm[(cc) * 4 + (kkv)][aoff + fm * 512];          \
  } while (0)

#define LOAD_B(cc, kkv, nh) do {                                               \
    bf0 = *(const f16x8*)&sm[(cc) * 4 + 2 + (kkv)][boff + (nh) * 1024];        \
    bf1 = *(const f16x8*)&sm[(cc) * 4 + 2 + (kkv)][boff + (nh) * 1024 + 512];  \
  } while (0)

#define DOMFMA(nh) do {                                                        \
    __builtin_amdgcn_s_setprio(1);                                             \
    _Pragma("unroll")                                                          \
    for (int fm = 0; fm < 8; fm++) {                                           \
      acc[fm][(nh) * 2]     = MFMA(af[fm], bf0, acc[fm][(nh) * 2]);            \
      acc[fm][(nh) * 2 + 1] = MFMA(af[fm], bf1, acc[fm][(nh) * 2 + 1]);        \
    }                                                                          \
    __builtin_amdgcn_s_setprio(0);                                             \
    SBAR();                                                                    \
  } while (0)

  const int nt = K >> 6;
  // prologue: stage tile 0 (units A0,B0,A1,B1) into buf 0; guard A0,B0
  STAGE(0, 0, 0, 0);
  STAGE(0, 1, 0, 0);
  STAGE(0, 0, 1, 0);
  STAGE(0, 1, 1, 0);
  VMCNT(4);
  BARRIER();

  for (int t = 0; t < nt - 1; ++t) {
    const int c = t & 1;
    const int kt1 = (t + 1) << 6;
    // ph0: reads A0(t),B0(t) [guarded at t-1.ph3 / prologue]
    LOAD_A(c, 0); LOAD_B(c, 0, 0);
    STAGE(c ^ 1, 0, 0, kt1);
    BARRIER();
    LGKM0();
    DOMFMA(0);
    BARRIER();
    // ph1: reads B0(t); checkpoint guards A1(t),B1(t) for ph2
    LOAD_B(c, 0, 1);
    STAGE(c ^ 1, 1, 0, kt1);
    BARRIER();
    LGKM0();
    DOMFMA(1);
    VMCNT(4);
    BARRIER();
    // ph2: reads A1(t),B1(t)
    LOAD_A(c, 1); LOAD_B(c, 1, 0);
    STAGE(c ^ 1, 0, 1, kt1);
    BARRIER();
    LGKM0();
    DOMFMA(0);
    BARRIER();
    // ph3: reads B1(t); checkpoint guards A0(t+1),B0(t+1) for next ph0
    LOAD_B(c, 1, 1);
    STAGE(c ^ 1, 1, 1, kt1);
    BARRIER();
    LGKM0();
    DOMFMA(1);
    VMCNT(4);
    BARRIER();
  }
  {  // last tile: no staging
    const int c = (nt - 1) & 1;
    LOAD_A(c, 0); LOAD_B(c, 0, 0);
    BARRIER();
    LGKM0();
    DOMFMA(0);
    BARRIER();
    LOAD_B(c, 0, 1);
    BARRIER();
    LGKM0();
    DOMFMA(1);
    VMCNT(0);
    BARRIER();
    LOAD_A(c, 1); LOAD_B(c, 1, 0);
    BARRIER();
    LGKM0();
    DOMFMA(0);
    BARRIER();
    LOAD_B(c, 1, 1);
    BARRIER();
    LGKM0();
    DOMFMA(1);
  }

#pragma unroll
  for (int fm = 0; fm < 8; fm++)
#pragma unroll
    for (int fn = 0; fn < 4; fn++)
#pragma unroll
      for (int q = 0; q < 4; q++) {
        size_t grow = (size_t)bx * 256 + wm * 128 + fm * 16 + kg * 4 + q;
        int gcol = by * 256 + wn * 64 + fn * 16 + lr;
        if (OUTF32)
          ((float*)Cg)[z * zC + grow * ldc + gcol] = acc[fm][fn][q];
        else
          ((f16*)Cg)[z * zC + grow * ldc + gcol] = (f16)acc[fm][fn][q];
      }
#undef STAGE
#undef LOAD_A
#undef LOAD_B
#undef DOMFMA
}

// ---------------------------------------------------------------------------
// Row softmax: SC row (2048 f32) -> Pb row (2048 f16)
// ---------------------------------------------------------------------------
__global__ __launch_bounds__(256)
void softmax_rows(const float* __restrict__ SC, f16* __restrict__ Pb) {
  const float* r = SC + (size_t)blockIdx.x * 2048;
  f16* po = Pb + (size_t)blockIdx.x * 2048;
  const int tid = threadIdx.x;
  f32x4 a = *(const f32x4*)(r + tid * 8);
  f32x4 b = *(const f32x4*)(r + tid * 8 + 4);
  float x[8] = {a[0], a[1], a[2], a[3], b[0], b[1], b[2], b[3]};
#pragma unroll
  for (int i = 0; i < 8; i++) x[i] = fminf(fmaxf(x[i], -1e30f), 1e30f);
  float m = x[0];
#pragma unroll
  for (int i = 1; i < 8; i++) m = fmaxf(m, x[i]);
#pragma unroll
  for (int off = 32; off; off >>= 1) m = fmaxf(m, __shfl_xor(m, off));
  __shared__ float rmax[4], rsum[4];
  const int w = tid >> 6, lane = tid & 63;
  if (!lane) rmax[w] = m;
  __syncthreads();
  m = fmaxf(fmaxf(rmax[0], rmax[1]), fmaxf(rmax[2], rmax[3]));
  float e[8], s = 0.f;
#pragma unroll
  for (int i = 0; i < 8; i++) {
    e[i] = __expf(x[i] - m);
    s += e[i];
  }
#pragma unroll
  for (int off = 32; off; off >>= 1) s += __shfl_xor(s, off);
  if (!lane) rsum[w] = s;
  __syncthreads();
  s = rsum[0] + rsum[1] + rsum[2] + rsum[3];
  float inv = 1.0f / s;
  f16x8 p;
#pragma unroll
  for (int i = 0; i < 8; i++) p[i] = (f16)(e[i] * inv);
  *(f16x8*)(po + tid * 8) = p;
}

// ---------------------------------------------------------------------------
extern "C" void kernel_launch(void* const* d_in, const int* in_sizes, int n_in,
                              void* d_out, int out_size, void* d_ws, size_t ws_size,
                              hipStream_t stream) {
  const float* S1 = (const float*)d_in[0];
  const float* S2 = (const float*)d_in[1];
  const float* W1 = (const float*)d_in[2];
  const float* W2 = (const float*)d_in[3];
  float* out = (float*)d_out;
  const int B = 8, N = 2048, H = 1024;
  const size_t NH = (size_t)N * H;  // 2M elems
  const size_t NN = (size_t)N * N;  // 4M elems
  const size_t WN = (size_t)H * H;  // 1M elems

  char* ws = (char*)d_ws;
  f16* W1h = (f16*)ws;
  f16* W2h = W1h + WN;
  size_t fixed = 2 * WN * sizeof(f16);  // 4 MB
  size_t perb = 5 * NH * sizeof(f16) + NN * sizeof(float) + NN * sizeof(f16);

  int bc = 1;
  const int cands[4] = {8, 4, 2, 1};
  for (int ci = 0; ci < 4; ci++) {
    if (fixed + (size_t)cands[ci] * perb <= ws_size) { bc = cands[ci]; break; }
  }
  f16* Ah = (f16*)(ws + fixed);       // S1 chunk f16
  f16* Bh = Ah + (size_t)bc * NH;     // S2 chunk f16
  f16* At = Bh + (size_t)bc * NH;     // S1 chunk transposed f16 [z][1024][2048]
  f16* Bt = At + (size_t)bc * NH;     // S2 chunk transposed
  f16* Kh = Bt + (size_t)bc * NH;     // proj output
  float* SC = (float*)(Kh + (size_t)bc * NH);
  f16* Pb = (f16*)(SC + (size_t)bc * NN);

  {
    int n4 = (int)(WN / 4);
    tof16x2_kernel<<<dim3((n4 + 255) / 256, 2), 256, 0, stream>>>(
        W1, W2, W1h, W2h, n4);
  }

  for (int c0 = 0; c0 < B; c0 += bc) {
    prep2_f16_kernel<<<dim3(N / 64, H / 64, 2 * bc), 256, 0, stream>>>(
        S1 + (size_t)c0 * NH, S2 + (size_t)c0 * NH, Ah, At, Bh, Bt, bc);

    for (int path = 0; path < 2; path++) {
      const f16* Qh = path ? Bh : Ah;  // query side (f16)
      const f16* Xh = path ? Ah : Bh;  // proj input (f16)
      const f16* Vt = path ? At : Bt;  // V transposed [z][1024][2048]
      const f16* Wh = path ? W2h : W1h;
      float* Op = out + (size_t)path * B * NH + (size_t)c0 * NH;

      // Kh = Xh @ W^T : M = bc*2048, N = 1024, K = 1024  (ZB=1, gx=bc*8)
      gemm256<0><<<dim3(bc * 32), 512, 0, stream>>>(
          Xh, 0, Wh, 0, Kh, 0, H, H, H, H, 1, bc * 8);
      // SC = Qh @ Kh^T per batch: 2048x2048, K = 1024  (ZB=bc, gx=8)
      gemm256<1><<<dim3(bc * 64), 512, 0, stream>>>(
          Qh, NH, Kh, NH, SC, NN, H, H, N, H, bc, 8);
      // softmax rows -> Pb f16
      softmax_rows<<<dim3(bc * N), 256, 0, stream>>>(SC, Pb);
      // O = Pb @ Vt^T : per batch 2048x1024, K = 2048  (ZB=bc, gx=8)
      gemm256<1><<<dim3(bc * 32), 512, 0, stream>>>(
          Pb, NN, Vt, NH, Op, NH, N, N, H, N, bc, 8);
    }
  }
}